// Round 10
// baseline (104.022 us; speedup 1.0000x reference)
//
#include <hip/hip_runtime.h>
#include <hip/hip_fp16.h>
#include <math.h>

// Problem constants (match reference)
#define NOUT      9                        // prod(out_shape)
#define N_ROWS_C  60000
#define NEDGE     960000
#define NGROUP    (NEDGE / 3)              // 320000
#define NCHUNK    (NGROUP / 256)           // 1250 chunks of 256 groups
#define NTILE     ((N_ROWS_C + 127) / 128) // 469 tiles of 128 rows
#define YH_STRIDE 32                       // halves per y row = 64 B = one cache line
// y row layout (halves): [0..8]=L0..L8, pad, [16..24]=R0..R8, pad

typedef float vfloat4 __attribute__((ext_vector_type(4)));  // native vector for nontemporal builtin

// ---------------------------------------------------------------------------
// DPP butterfly reduction over aligned 8-lane groups (masks {1,2,7}).
// ---------------------------------------------------------------------------
template <int CTRL>
__device__ __forceinline__ float dpp_xor_add(float v) {
    int r = __builtin_amdgcn_update_dpp(0, __float_as_int(v), CTRL, 0xf, 0xf, true);
    return v + __int_as_float(r);
}
__device__ __forceinline__ float red8(float v) {
    v = dpp_xor_add<0xB1>(v);   // xor 1 (quad_perm 1,0,3,2)
    v = dpp_xor_add<0x4E>(v);   // xor 2 (quad_perm 2,3,0,1)
    v = dpp_xor_add<0x141>(v);  // xor 7 (row_half_mirror)
    return v;
}

// fast tanh: tanh(v) = 1 - 2/(1+e^{2v});  v_exp_f32 computes 2^x
__device__ __forceinline__ float fast_tanh(float v) {
    float e = __builtin_amdgcn_exp2f(v * 2.8853900817779268f);
    return 1.0f - 2.0f * __builtin_amdgcn_rcpf(e + 1.0f);
}

__device__ __forceinline__ unsigned int pk(float a, float b) {
    __half2 h = __floats2half2_rn(a, b);
    return *reinterpret_cast<unsigned int*>(&h);
}

__device__ __forceinline__ void acc9(float* a, uint4 v, unsigned int v4) {
    float2 f;
    f = __half22float2(*reinterpret_cast<__half2*>(&v.x)); a[0] += f.x; a[1] += f.y;
    f = __half22float2(*reinterpret_cast<__half2*>(&v.y)); a[2] += f.x; a[3] += f.y;
    f = __half22float2(*reinterpret_cast<__half2*>(&v.z)); a[4] += f.x; a[5] += f.y;
    f = __half22float2(*reinterpret_cast<__half2*>(&v.w)); a[6] += f.x; a[7] += f.y;
    f = __half22float2(*reinterpret_cast<__half2*>(&v4));  a[8] += f.x;
}

__device__ __forceinline__ void store_row(__half* __restrict__ yh, int r,
                                          const float* aL, const float* aR) {
    __half* yr = yh + (size_t)r * YH_STRIDE;
    *reinterpret_cast<uint4*>(yr) =
        make_uint4(pk(aL[0],aL[1]), pk(aL[2],aL[3]), pk(aL[4],aL[5]), pk(aL[6],aL[7]));
    *reinterpret_cast<uint2*>(yr + 8)  = make_uint2(pk(aL[8], 0.f), 0u);
    *reinterpret_cast<uint4*>(yr + 16) =
        make_uint4(pk(aR[0],aR[1]), pk(aR[2],aR[3]), pk(aR[4],aR[5]), pk(aR[6],aR[7]));
    *reinterpret_cast<uint2*>(yr + 24) = make_uint2(pk(aR[8], 0.f), 0u);
}

// ---------------------------------------------------------------------------
// Kernel 1: y[i] = fp16 [x[i].Wl | x[i].Wr]. 8 lanes per row (k-split),
// 4 rows per lane; W staged in LDS (conflict-free: 8 distinct float4 ->
// 32 banks, 8-way broadcast). x loads non-temporal (read-once; keep L2/L3
// clean so the y table survives to the gather kernel).
// ---------------------------------------------------------------------------
__global__ __launch_bounds__(256, 2) void precompute_y(
    const float* __restrict__ x, const float* __restrict__ W, __half* __restrict__ yh)
{
    __shared__ float4 sW[576];               // 9 rows x 64 float4 = 9 KB
    const int t = threadIdx.x;
    const float4* __restrict__ Wv = reinterpret_cast<const float4*>(W);
    for (int i = t; i < 576; i += 256) sW[i] = Wv[i];

    const int s    = t & 7;                  // k-subchunk
    const int slot = t >> 3;                 // row slot 0..31
    const int base = blockIdx.x * 128;
    const int r0   = base + slot;            // <= 59935
    const int r1   = base + 32 + slot;       // <= 59967
    const int r2   = base + 64 + slot;       // <= 59999
    const int r3   = base + 96 + slot;       // <= 60031 (needs guard)
    const int r3c  = (r3 < N_ROWS_C) ? r3 : 0;

    __syncthreads();

    const vfloat4* __restrict__ xv = reinterpret_cast<const vfloat4*>(x);

    float aL[4][NOUT], aR[4][NOUT];
#pragma unroll
    for (int rr = 0; rr < 4; ++rr)
#pragma unroll
        for (int j = 0; j < NOUT; ++j) { aL[rr][j] = 0.f; aR[rr][j] = 0.f; }

#pragma unroll
    for (int q = 0; q < 4; ++q) {
        const int f = s + 8 * q;             // float4 index 0..31 within row
        vfloat4 xr[4];
        xr[0] = __builtin_nontemporal_load(xv + (size_t)r0  * 32 + f);
        xr[1] = __builtin_nontemporal_load(xv + (size_t)r1  * 32 + f);
        xr[2] = __builtin_nontemporal_load(xv + (size_t)r2  * 32 + f);
        xr[3] = __builtin_nontemporal_load(xv + (size_t)r3c * 32 + f);
#pragma unroll
        for (int j = 0; j < NOUT; ++j) {
            float4 wl = sW[j * 64 + f];       // left half  (k 0..127)
            float4 wr = sW[j * 64 + 32 + f];  // right half (k 128..255)
#pragma unroll
            for (int rr = 0; rr < 4; ++rr) {
                aL[rr][j] += xr[rr].x * wl.x + xr[rr].y * wl.y + xr[rr].z * wl.z + xr[rr].w * wl.w;
                aR[rr][j] += xr[rr].x * wr.x + xr[rr].y * wr.y + xr[rr].z * wr.z + xr[rr].w * wr.w;
            }
        }
    }

#pragma unroll
    for (int rr = 0; rr < 4; ++rr)
#pragma unroll
        for (int j = 0; j < NOUT; ++j) {
            aL[rr][j] = red8(aL[rr][j]);
            aR[rr][j] = red8(aR[rr][j]);
        }

    if (s == 0)      store_row(yh, r0, aL[0], aR[0]);
    else if (s == 1) store_row(yh, r1, aL[1], aR[1]);
    else if (s == 2) store_row(yh, r2, aL[2], aR[2]);
    else if (s == 3 && r3 < N_ROWS_C) store_row(yh, r3, aL[3], aR[3]);
}

// ---------------------------------------------------------------------------
// Kernel 2: out[g][j] = tanh( sum_{e in group g} yL[row_e][j] + yR[col_e][j] )
// No LDS at all: indices as one dwordx3 per endpoint-set; output as 3
// packed 12-B stores. A wave's 9-float outputs tile a contiguous 2304-B
// span, so each dwordx3 store instruction is full-line coalesced by the TA.
// ---------------------------------------------------------------------------
struct idx3 { int a, b, c; };
struct f3   { float x, y, z; };

__global__ __launch_bounds__(256) void gather_tanh(
    const int* __restrict__ eidx, const __half* __restrict__ yh, float* __restrict__ out)
{
    const int t = threadIdx.x;
    const int g = blockIdx.x * 256 + t;      // this thread's group

    idx3 rv = *reinterpret_cast<const idx3*>(eidx + 3 * (size_t)g);
    idx3 cv = *reinterpret_cast<const idx3*>(eidx + NEDGE + 3 * (size_t)g);
    const int rIdx[3] = { rv.a, rv.b, rv.c };
    const int cIdx[3] = { cv.a, cv.b, cv.c };

    float a[NOUT];
#pragma unroll
    for (int j = 0; j < NOUT; ++j) a[j] = 0.f;

#pragma unroll
    for (int p = 0; p < 3; ++p) {
        {
            const unsigned int* pr =
                reinterpret_cast<const unsigned int*>(yh + (size_t)rIdx[p] * YH_STRIDE);
            uint4 v = *reinterpret_cast<const uint4*>(pr);   // L0..L7
            acc9(a, v, pr[4]);                               // + L8
        }
        {
            const unsigned int* pc =
                reinterpret_cast<const unsigned int*>(yh + (size_t)cIdx[p] * YH_STRIDE + 16);
            uint4 v = *reinterpret_cast<const uint4*>(pc);   // R0..R7
            acc9(a, v, pc[4]);                               // + R8
        }
    }

    float* o = out + (size_t)g * NOUT;
    f3 s0 = { fast_tanh(a[0]), fast_tanh(a[1]), fast_tanh(a[2]) };
    f3 s1 = { fast_tanh(a[3]), fast_tanh(a[4]), fast_tanh(a[5]) };
    f3 s2 = { fast_tanh(a[6]), fast_tanh(a[7]), fast_tanh(a[8]) };
    reinterpret_cast<f3*>(o)[0] = s0;
    reinterpret_cast<f3*>(o)[1] = s1;
    reinterpret_cast<f3*>(o)[2] = s2;
}

extern "C" void kernel_launch(void* const* d_in, const int* in_sizes, int n_in,
                              void* d_out, int out_size, void* d_ws, size_t ws_size,
                              hipStream_t stream) {
    const float* x    = (const float*)d_in[0];   // [60000, 128] fp32
    const float* W    = (const float*)d_in[1];   // [9, 256] fp32
    const int*   eidx = (const int*)d_in[2];     // [2, 960000] int32
    float*       out  = (float*)d_out;           // [320000, 9] fp32
    __half*      yh   = (__half*)d_ws;           // [60000, 32] fp16 scratch (3.84 MB)

    precompute_y<<<NTILE, 256, 0, stream>>>(x, W, yh);
    gather_tanh<<<NCHUNK, 256, 0, stream>>>(eidx, yh, out);
}

// Round 11
// 99.185 us; speedup vs baseline: 1.0488x; 1.0488x over previous
//
#include <hip/hip_runtime.h>
#include <hip/hip_fp16.h>
#include <math.h>

// Problem constants (match reference)
#define NOUT      9                        // prod(out_shape)
#define N_ROWS_C  60000
#define NEDGE     960000
#define NGROUP    (NEDGE / 3)              // 320000
#define NCHUNK    (NGROUP / 256)           // 1250 chunks of 256 groups
#define NTILE     ((N_ROWS_C + 127) / 128) // 469 tiles of 128 rows
#define YH_STRIDE 32                       // halves per y row = 64 B = one cache line
// y row layout (halves): [0..8]=L0..L8, pad, [16..24]=R0..R8, pad

// ---------------------------------------------------------------------------
// DPP butterfly reduction over aligned 8-lane groups (masks {1,2,7}).
// ---------------------------------------------------------------------------
template <int CTRL>
__device__ __forceinline__ float dpp_xor_add(float v) {
    int r = __builtin_amdgcn_update_dpp(0, __float_as_int(v), CTRL, 0xf, 0xf, true);
    return v + __int_as_float(r);
}
__device__ __forceinline__ float red8(float v) {
    v = dpp_xor_add<0xB1>(v);   // xor 1 (quad_perm 1,0,3,2)
    v = dpp_xor_add<0x4E>(v);   // xor 2 (quad_perm 2,3,0,1)
    v = dpp_xor_add<0x141>(v);  // xor 7 (row_half_mirror)
    return v;
}

// fast tanh: tanh(v) = 1 - 2/(1+e^{2v});  v_exp_f32 computes 2^x
__device__ __forceinline__ float fast_tanh(float v) {
    float e = __builtin_amdgcn_exp2f(v * 2.8853900817779268f);
    return 1.0f - 2.0f * __builtin_amdgcn_rcpf(e + 1.0f);
}

__device__ __forceinline__ unsigned int pk(float a, float b) {
    __half2 h = __floats2half2_rn(a, b);
    return *reinterpret_cast<unsigned int*>(&h);
}

__device__ __forceinline__ void acc9(float* a, uint4 v, unsigned int v4) {
    float2 f;
    f = __half22float2(*reinterpret_cast<__half2*>(&v.x)); a[0] += f.x; a[1] += f.y;
    f = __half22float2(*reinterpret_cast<__half2*>(&v.y)); a[2] += f.x; a[3] += f.y;
    f = __half22float2(*reinterpret_cast<__half2*>(&v.z)); a[4] += f.x; a[5] += f.y;
    f = __half22float2(*reinterpret_cast<__half2*>(&v.w)); a[6] += f.x; a[7] += f.y;
    f = __half22float2(*reinterpret_cast<__half2*>(&v4));  a[8] += f.x;
}

__device__ __forceinline__ void store_row(__half* __restrict__ yh, int r,
                                          const float* aL, const float* aR) {
    __half* yr = yh + (size_t)r * YH_STRIDE;
    *reinterpret_cast<uint4*>(yr) =
        make_uint4(pk(aL[0],aL[1]), pk(aL[2],aL[3]), pk(aL[4],aL[5]), pk(aL[6],aL[7]));
    *reinterpret_cast<uint2*>(yr + 8)  = make_uint2(pk(aL[8], 0.f), 0u);
    *reinterpret_cast<uint4*>(yr + 16) =
        make_uint4(pk(aR[0],aR[1]), pk(aR[2],aR[3]), pk(aR[4],aR[5]), pk(aR[6],aR[7]));
    *reinterpret_cast<uint2*>(yr + 24) = make_uint2(pk(aR[8], 0.f), 0u);
}

// ---------------------------------------------------------------------------
// Kernel 1: y[i] = fp16 [x[i].Wl | x[i].Wr]. 8 lanes per row (k-split),
// 4 rows per lane; W staged in LDS (conflict-free: 8 distinct float4 ->
// 32 banks, 8-way broadcast). Plain float4 x loads (nt hint regressed in R10).
// ---------------------------------------------------------------------------
__global__ __launch_bounds__(256, 2) void precompute_y(
    const float* __restrict__ x, const float* __restrict__ W, __half* __restrict__ yh)
{
    __shared__ float4 sW[576];               // 9 rows x 64 float4 = 9 KB
    const int t = threadIdx.x;
    const float4* __restrict__ Wv = reinterpret_cast<const float4*>(W);
    for (int i = t; i < 576; i += 256) sW[i] = Wv[i];

    const int s    = t & 7;                  // k-subchunk
    const int slot = t >> 3;                 // row slot 0..31
    const int base = blockIdx.x * 128;
    const int r0   = base + slot;            // <= 59935
    const int r1   = base + 32 + slot;       // <= 59967
    const int r2   = base + 64 + slot;       // <= 59999
    const int r3   = base + 96 + slot;       // <= 60031 (needs guard)
    const int r3c  = (r3 < N_ROWS_C) ? r3 : 0;

    __syncthreads();

    const float4* __restrict__ xv = reinterpret_cast<const float4*>(x);

    float aL[4][NOUT], aR[4][NOUT];
#pragma unroll
    for (int rr = 0; rr < 4; ++rr)
#pragma unroll
        for (int j = 0; j < NOUT; ++j) { aL[rr][j] = 0.f; aR[rr][j] = 0.f; }

#pragma unroll
    for (int q = 0; q < 4; ++q) {
        const int f = s + 8 * q;             // float4 index 0..31 within row
        float4 xr[4];
        xr[0] = xv[(size_t)r0  * 32 + f];
        xr[1] = xv[(size_t)r1  * 32 + f];
        xr[2] = xv[(size_t)r2  * 32 + f];
        xr[3] = xv[(size_t)r3c * 32 + f];
#pragma unroll
        for (int j = 0; j < NOUT; ++j) {
            float4 wl = sW[j * 64 + f];       // left half  (k 0..127)
            float4 wr = sW[j * 64 + 32 + f];  // right half (k 128..255)
#pragma unroll
            for (int rr = 0; rr < 4; ++rr) {
                aL[rr][j] += xr[rr].x * wl.x + xr[rr].y * wl.y + xr[rr].z * wl.z + xr[rr].w * wl.w;
                aR[rr][j] += xr[rr].x * wr.x + xr[rr].y * wr.y + xr[rr].z * wr.z + xr[rr].w * wr.w;
            }
        }
    }

#pragma unroll
    for (int rr = 0; rr < 4; ++rr)
#pragma unroll
        for (int j = 0; j < NOUT; ++j) {
            aL[rr][j] = red8(aL[rr][j]);
            aR[rr][j] = red8(aR[rr][j]);
        }

    if (s == 0)      store_row(yh, r0, aL[0], aR[0]);
    else if (s == 1) store_row(yh, r1, aL[1], aR[1]);
    else if (s == 2) store_row(yh, r2, aL[2], aR[2]);
    else if (s == 3 && r3 < N_ROWS_C) store_row(yh, r3, aL[3], aR[3]);
}

// ---------------------------------------------------------------------------
// Kernel 2: out[g][j] = tanh( sum_{e in group g} yL[row_e][j] + yR[col_e][j] )
// Indices via direct dwordx3 loads (no staging barrier); output via sOut LDS
// transpose for dense coalesced stores (9 dword-store instrs, 4 lines/instr —
// the R10 LDS-free f3 variant regressed: 36 B inter-lane stride per instr).
// ---------------------------------------------------------------------------
struct idx3 { int a, b, c; };

__global__ __launch_bounds__(256) void gather_tanh(
    const int* __restrict__ eidx, const __half* __restrict__ yh, float* __restrict__ out)
{
    __shared__ float sOut[NOUT * 256];

    const int t = threadIdx.x;
    const int g = blockIdx.x * 256 + t;      // this thread's group

    idx3 rv = *reinterpret_cast<const idx3*>(eidx + 3 * (size_t)g);
    idx3 cv = *reinterpret_cast<const idx3*>(eidx + NEDGE + 3 * (size_t)g);
    const int rIdx[3] = { rv.a, rv.b, rv.c };
    const int cIdx[3] = { cv.a, cv.b, cv.c };

    float a[NOUT];
#pragma unroll
    for (int j = 0; j < NOUT; ++j) a[j] = 0.f;

#pragma unroll
    for (int p = 0; p < 3; ++p) {
        {
            const unsigned int* pr =
                reinterpret_cast<const unsigned int*>(yh + (size_t)rIdx[p] * YH_STRIDE);
            uint4 v = *reinterpret_cast<const uint4*>(pr);   // L0..L7
            acc9(a, v, pr[4]);                               // + L8
        }
        {
            const unsigned int* pc =
                reinterpret_cast<const unsigned int*>(yh + (size_t)cIdx[p] * YH_STRIDE + 16);
            uint4 v = *reinterpret_cast<const uint4*>(pc);   // R0..R7
            acc9(a, v, pc[4]);                               // + R8
        }
    }

#pragma unroll
    for (int j = 0; j < NOUT; ++j) sOut[t * NOUT + j] = fast_tanh(a[j]);
    __syncthreads();

    float* o = out + (size_t)blockIdx.x * 256 * NOUT;
#pragma unroll
    for (int j = 0; j < NOUT; ++j) {
        o[t + 256 * j] = sOut[t + 256 * j];
    }
}

extern "C" void kernel_launch(void* const* d_in, const int* in_sizes, int n_in,
                              void* d_out, int out_size, void* d_ws, size_t ws_size,
                              hipStream_t stream) {
    const float* x    = (const float*)d_in[0];   // [60000, 128] fp32
    const float* W    = (const float*)d_in[1];   // [9, 256] fp32
    const int*   eidx = (const int*)d_in[2];     // [2, 960000] int32
    float*       out  = (float*)d_out;           // [320000, 9] fp32
    __half*      yh   = (__half*)d_ws;           // [60000, 32] fp16 scratch (3.84 MB)

    precompute_y<<<NTILE, 256, 0, stream>>>(x, W, yh);
    gather_tanh<<<NCHUNK, 256, 0, stream>>>(eidx, yh, out);
}